// Round 1
// baseline (790.189 us; speedup 1.0000x reference)
//
#include <hip/hip_runtime.h>

// ---------------------------------------------------------------------------
// MHA forward: out = softmax((XWq^T+bq)(XWk^T+bk)^T / sqrt(dk)) (XWv^T+bv) Wo^T + bo
// B=2 S=4096 D=1024 H=16 DK=64.  All matmuls in bf16 MFMA (16x16x32), fp32 acc.
// Workspace layout (bf16 elems): Xq,Xk,Xv (3x8192x1024) | Wq,Wk,Wv,Wo (4x1024^2)
//                              | Q,K,V (3x8192x1024) | AO (8192x1024)  ~126 MB
// ---------------------------------------------------------------------------

typedef __bf16 bf16x8 __attribute__((ext_vector_type(8)));
typedef __bf16 bf16x4 __attribute__((ext_vector_type(4)));
typedef float  f32x4  __attribute__((ext_vector_type(4)));

#define MFMA16(a, b, c) __builtin_amdgcn_mfma_f32_16x16x32_bf16(a, b, c, 0, 0, 0)

constexpr int D_MODEL = 1024;
constexpr int SEQ     = 4096;
constexpr int BATCH   = 2;
constexpr int NH      = 16;
constexpr int DKH     = 64;
constexpr int MROWS   = BATCH * SEQ;  // 8192

// ---------------------------------------------------------------- cast kernel
__global__ void cast_f32_bf16(const float* __restrict__ in,
                              __bf16* __restrict__ out, int n) {
  int i = (blockIdx.x * 256 + threadIdx.x) * 4;
  if (i >= n) return;
  float4 v = *(const float4*)(in + i);
  bf16x4 o;
  o[0] = (__bf16)v.x; o[1] = (__bf16)v.y; o[2] = (__bf16)v.z; o[3] = (__bf16)v.w;
  *(bf16x4*)(out + i) = o;
}

// ------------------------------------------------------------------ GEMM (BT)
// C[M,N] = A[M,K] * W[N,K]^T + bias.  128x128 tile, BK=32, 4 waves (2x2),
// each wave 64x64 = 4x4 MFMA tiles.  LDS chunk-XOR swizzle: rows are 4 chunks
// of 16B; store chunk c at c ^ ((row>>1)&3)  ->  frag ds_read_b128 is 2-way
// bank aliased (free), staging writes likewise.
template <bool OUTF32>
__global__ __launch_bounds__(256) void gemm_bt(
    const __bf16* __restrict__ Abase, const __bf16* __restrict__ Wbase,
    const float* __restrict__ b0, const float* __restrict__ b1,
    const float* __restrict__ b2, void* __restrict__ Obase) {
  constexpr int K = 1024, N = 1024;
  const int z = blockIdx.z;
  const __bf16* A = Abase + (size_t)z * MROWS * K;
  const __bf16* W = Wbase + (size_t)z * N * K;
  const float* bias = (z == 0) ? b0 : (z == 1 ? b1 : b2);

  const int bm0 = blockIdx.x * 128, bn0 = blockIdx.y * 128;
  const int tid = threadIdx.x;
  const int lane = tid & 63, w = tid >> 6;
  const int wr = w >> 1, wc = w & 1;
  const int quad = lane >> 4, l15 = lane & 15;

  __shared__ __align__(16) __bf16 As[128 * 32];
  __shared__ __align__(16) __bf16 Bs[128 * 32];

  // staging: thread t -> row t/2, chunk pair (t&1)*2 .. +1
  const int srow = tid >> 1;
  const int sc2 = (tid & 1) * 2;
  const __bf16* Ag = A + (size_t)(bm0 + srow) * K;
  const __bf16* Wg = W + (size_t)(bn0 + srow) * K;
  const int so0 = srow * 32 + (((sc2 + 0) ^ ((srow >> 1) & 3)) << 3);
  const int so1 = srow * 32 + (((sc2 + 1) ^ ((srow >> 1) & 3)) << 3);

  f32x4 acc[4][4];
  for (int i = 0; i < 4; i++)
    for (int j = 0; j < 4; j++) acc[i][j] = f32x4{0.f, 0.f, 0.f, 0.f};

  int aoff[4], boff[4];
  for (int i = 0; i < 4; i++) {
    int ra = wr * 64 + i * 16 + l15;
    aoff[i] = ra * 32 + ((quad ^ ((ra >> 1) & 3)) << 3);
    int rb = wc * 64 + i * 16 + l15;
    boff[i] = rb * 32 + ((quad ^ ((rb >> 1) & 3)) << 3);
  }

  for (int k0 = 0; k0 < K; k0 += 32) {
    uint4 av0 = *(const uint4*)(Ag + k0 + sc2 * 8);
    uint4 av1 = *(const uint4*)(Ag + k0 + sc2 * 8 + 8);
    uint4 bv0 = *(const uint4*)(Wg + k0 + sc2 * 8);
    uint4 bv1 = *(const uint4*)(Wg + k0 + sc2 * 8 + 8);
    __syncthreads();  // previous iter's frag reads complete
    *(uint4*)(As + so0) = av0;
    *(uint4*)(As + so1) = av1;
    *(uint4*)(Bs + so0) = bv0;
    *(uint4*)(Bs + so1) = bv1;
    __syncthreads();
    bf16x8 af[4], bfr[4];
    for (int i = 0; i < 4; i++) af[i] = *(const bf16x8*)(As + aoff[i]);
    for (int j = 0; j < 4; j++) bfr[j] = *(const bf16x8*)(Bs + boff[j]);
    for (int i = 0; i < 4; i++)
      for (int j = 0; j < 4; j++) acc[i][j] = MFMA16(af[i], bfr[j], acc[i][j]);
  }

  // epilogue: C/D layout col=lane&15, row=quad*4+reg
  for (int j = 0; j < 4; j++) {
    int gcol = bn0 + wc * 64 + j * 16 + l15;
    float bv = bias[gcol];
    for (int i = 0; i < 4; i++) {
      int grow0 = bm0 + wr * 64 + i * 16 + quad * 4;
      for (int r = 0; r < 4; r++) {
        float v = acc[i][j][r] + bv;
        size_t idx = (size_t)(grow0 + r) * N + gcol;
        if constexpr (OUTF32)
          ((float*)Obase)[idx] = v;
        else
          (((__bf16*)Obase) + (size_t)z * MROWS * N)[idx] = (__bf16)v;
      }
    }
  }
}

// ----------------------------------------------------------- flash attention
// grid (S/64, NH, B), block 256 (4 waves).  Wave w owns q rows w*16..w*16+15
// of the 64-row Q tile.  K-tiles of 64; online softmax; P round-trips LDS
// into A-operand layout; V staged transposed so PV B-frags are b128 reads.
// 64-elem (128B) LDS rows: chunk swizzle c ^ (row&7) -> 2-way aliasing (free).
__device__ __forceinline__ int sw64(int row, int c) {
  return row * 64 + ((c ^ (row & 7)) << 3);
}

__global__ __launch_bounds__(256) void attn_kernel(
    const __bf16* __restrict__ Q, const __bf16* __restrict__ K,
    const __bf16* __restrict__ V, __bf16* __restrict__ O) {
  const int qt = blockIdx.x, h = blockIdx.y, b = blockIdx.z;
  const size_t base = (size_t)b * SEQ * D_MODEL + h * DKH;
  const __bf16* Qg = Q + base + (size_t)qt * 64 * D_MODEL;
  const __bf16* Kg = K + base;
  const __bf16* Vg = V + base;

  __shared__ __align__(16) __bf16 Qs[64 * 64];
  __shared__ __align__(16) __bf16 Ks[64 * 64];
  __shared__ __align__(16) __bf16 Vts[64 * 64];  // [d][kv]
  __shared__ __align__(16) __bf16 Ps[64 * 64];   // [q][kv], per-wave 16-row band

  const int tid = threadIdx.x;
  const int lane = tid & 63, w = tid >> 6;
  const int quad = lane >> 4, l15 = lane & 15;

  // stage Q tile: thread t -> row t/4, chunks (t&3)*2 .. +1
  {
    int row = tid >> 2, cb = (tid & 3) * 2;
    uint4 v0 = *(const uint4*)(Qg + (size_t)row * D_MODEL + cb * 8);
    uint4 v1 = *(const uint4*)(Qg + (size_t)row * D_MODEL + cb * 8 + 8);
    *(uint4*)(Qs + sw64(row, cb)) = v0;
    *(uint4*)(Qs + sw64(row, cb + 1)) = v1;
  }
  __syncthreads();

  // Q frags are loop-invariant: A[m=lane&15][k=quad*8+j], k-steps 0 and 1
  bf16x8 qf[2];
  {
    int qrow = w * 16 + l15;
    qf[0] = *(const bf16x8*)(Qs + sw64(qrow, quad));
    qf[1] = *(const bf16x8*)(Qs + sw64(qrow, 4 + quad));
  }

  float m_[4], l_[4];
  f32x4 o_[4];
  for (int r = 0; r < 4; r++) { m_[r] = -__builtin_inff(); l_[r] = 0.f; }
  for (int j = 0; j < 4; j++) o_[j] = f32x4{0.f, 0.f, 0.f, 0.f};

  for (int kt = 0; kt < SEQ / 64; ++kt) {
    __syncthreads();  // prior iter's K/V frag reads done before overwrite
    {
      int row = tid >> 2, cb = (tid & 3) * 2;
      const __bf16* kg = Kg + (size_t)(kt * 64 + row) * D_MODEL;
      uint4 v0 = *(const uint4*)(kg + cb * 8);
      uint4 v1 = *(const uint4*)(kg + cb * 8 + 8);
      *(uint4*)(Ks + sw64(row, cb)) = v0;
      *(uint4*)(Ks + sw64(row, cb + 1)) = v1;
      // V transposed: thread reads V[kv=row][d0..d0+15], writes Vts[d][kv]
      const __bf16* vg = Vg + (size_t)(kt * 64 + row) * D_MODEL + (tid & 3) * 16;
      union { uint4 u; __bf16 e[8]; } a0, a1;
      a0.u = *(const uint4*)(vg);
      a1.u = *(const uint4*)(vg + 8);
      int d0 = (tid & 3) * 16;
      int c = row >> 3, wi = row & 7;
      for (int j = 0; j < 8; j++) {
        int d = d0 + j;
        Vts[d * 64 + ((c ^ (d & 7)) << 3) + wi] = a0.e[j];
        int d2 = d0 + 8 + j;
        Vts[d2 * 64 + ((c ^ (d2 & 7)) << 3) + wi] = a1.e[j];
      }
    }
    __syncthreads();

    // S = Q K^T / sqrt(dk):  sc[j] covers cols j*16.., rows quad*4+reg
    f32x4 sc[4];
    for (int j = 0; j < 4; j++) {
      int krow = j * 16 + l15;
      bf16x8 kf0 = *(const bf16x8*)(Ks + sw64(krow, quad));
      bf16x8 kf1 = *(const bf16x8*)(Ks + sw64(krow, 4 + quad));
      sc[j] = f32x4{0.f, 0.f, 0.f, 0.f};
      sc[j] = MFMA16(qf[0], kf0, sc[j]);
      sc[j] = MFMA16(qf[1], kf1, sc[j]);
      sc[j] *= 0.125f;  // 1/sqrt(64)
    }

    // online softmax: rows live in 16-lane quads; reduce across lanes
    float alpha[4], rs[4];
    for (int r = 0; r < 4; r++) {
      float v = fmaxf(fmaxf(sc[0][r], sc[1][r]), fmaxf(sc[2][r], sc[3][r]));
      v = fmaxf(v, __shfl_xor(v, 1));
      v = fmaxf(v, __shfl_xor(v, 2));
      v = fmaxf(v, __shfl_xor(v, 4));
      v = fmaxf(v, __shfl_xor(v, 8));
      float mn = fmaxf(m_[r], v);
      alpha[r] = __expf(m_[r] - mn);
      m_[r] = mn;
      rs[r] = 0.f;
    }
    for (int j = 0; j < 4; j++)
      for (int r = 0; r < 4; r++) {
        float p = __expf(sc[j][r] - m_[r]);
        sc[j][r] = p;
        rs[r] += p;
      }
    for (int r = 0; r < 4; r++) {
      float s = rs[r];
      s += __shfl_xor(s, 1);
      s += __shfl_xor(s, 2);
      s += __shfl_xor(s, 4);
      s += __shfl_xor(s, 8);
      l_[r] = l_[r] * alpha[r] + s;
      o_[0][r] *= alpha[r]; o_[1][r] *= alpha[r];
      o_[2][r] *= alpha[r]; o_[3][r] *= alpha[r];
    }

    // P -> LDS (C-layout -> A-operand layout), wave-private 16-row band
    for (int j = 0; j < 4; j++)
      for (int r = 0; r < 4; r++) {
        int prow = w * 16 + quad * 4 + r;
        int pcol = j * 16 + l15;
        Ps[prow * 64 + (((pcol >> 3) ^ (prow & 7)) << 3) + (pcol & 7)] =
            (__bf16)sc[j][r];
      }
    asm volatile("s_waitcnt lgkmcnt(0)" ::: "memory");  // intra-wave ds order

    // O += P V:  A=P[q][kv], B[k=kv][n=d] = Vts[d][kv]
    {
      int prow = w * 16 + l15;
      bf16x8 pf0 = *(const bf16x8*)(Ps + sw64(prow, quad));
      bf16x8 pf1 = *(const bf16x8*)(Ps + sw64(prow, 4 + quad));
      for (int j = 0; j < 4; j++) {
        int drow = j * 16 + l15;
        bf16x8 vf0 = *(const bf16x8*)(Vts + sw64(drow, quad));
        bf16x8 vf1 = *(const bf16x8*)(Vts + sw64(drow, 4 + quad));
        o_[j] = MFMA16(pf0, vf0, o_[j]);
        o_[j] = MFMA16(pf1, vf1, o_[j]);
      }
    }
  }

  // epilogue: O /= l, store bf16
  for (int r = 0; r < 4; r++) {
    float inv = 1.f / l_[r];
    int grow = qt * 64 + w * 16 + quad * 4 + r;
    __bf16* og = O + ((size_t)b * SEQ + grow) * D_MODEL + h * DKH;
    for (int j = 0; j < 4; j++) og[j * 16 + l15] = (__bf16)(o_[j][r] * inv);
  }
}

// ---------------------------------------------------------------------------
extern "C" void kernel_launch(void* const* d_in, const int* in_sizes, int n_in,
                              void* d_out, int out_size, void* d_ws,
                              size_t ws_size, hipStream_t stream) {
  const float* q  = (const float*)d_in[0];
  const float* k  = (const float*)d_in[1];
  const float* v  = (const float*)d_in[2];
  const float* Wq = (const float*)d_in[3];
  const float* bq = (const float*)d_in[4];
  const float* Wk = (const float*)d_in[5];
  const float* bk = (const float*)d_in[6];
  const float* Wv = (const float*)d_in[7];
  const float* bv = (const float*)d_in[8];
  const float* Wo = (const float*)d_in[9];
  const float* bo = (const float*)d_in[10];

  const size_t MD = (size_t)MROWS * D_MODEL;    // 8388608
  const size_t WW = (size_t)D_MODEL * D_MODEL;  // 1048576

  __bf16* ws  = (__bf16*)d_ws;  // needs ~126 MB of workspace
  __bf16* Xq  = ws;
  __bf16* Xk  = Xq + MD;
  __bf16* Xv  = Xk + MD;
  __bf16* Wqb = Xv + MD;
  __bf16* Wkb = Wqb + WW;
  __bf16* Wvb = Wkb + WW;
  __bf16* Wob = Wvb + WW;
  __bf16* Qp  = Wob + WW;
  __bf16* Kp  = Qp + MD;
  __bf16* Vp  = Kp + MD;
  __bf16* AO  = Vp + MD;

  // fp32 -> bf16 casts (each thread handles 4 elems)
  cast_f32_bf16<<<8192, 256, 0, stream>>>(q, Xq, (int)MD);
  cast_f32_bf16<<<8192, 256, 0, stream>>>(k, Xk, (int)MD);
  cast_f32_bf16<<<8192, 256, 0, stream>>>(v, Xv, (int)MD);
  cast_f32_bf16<<<1024, 256, 0, stream>>>(Wq, Wqb, (int)WW);
  cast_f32_bf16<<<1024, 256, 0, stream>>>(Wk, Wkb, (int)WW);
  cast_f32_bf16<<<1024, 256, 0, stream>>>(Wv, Wvb, (int)WW);
  cast_f32_bf16<<<1024, 256, 0, stream>>>(Wo, Wob, (int)WW);

  // fused QKV projections (z selects A / W / bias / out)
  gemm_bt<false><<<dim3(MROWS / 128, D_MODEL / 128, 3), 256, 0, stream>>>(
      Xq, Wqb, bq, bk, bv, (void*)Qp);

  // flash attention
  attn_kernel<<<dim3(SEQ / 64, NH, BATCH), 256, 0, stream>>>(Qp, Kp, Vp, AO);

  // output projection -> fp32 d_out
  gemm_bt<true><<<dim3(MROWS / 128, D_MODEL / 128, 1), 256, 0, stream>>>(
      AO, Wob, bo, bo, bo, d_out);
}

// Round 2
// 500.201 us; speedup vs baseline: 1.5797x; 1.5797x over previous
//
#include <hip/hip_runtime.h>

// ---------------------------------------------------------------------------
// MHA forward. B=2 S=4096 D=1024 H=16 DK=64. bf16 MFMA 16x16x32, fp32 acc.
// R2: attention restructured — St = K*Q^T (transposed scores), O^T = V^T*P^T,
// q=64/wave, pre-transposed V from projection GEMM, stride-72 LDS (no XOR),
// packed b64 P writes, 1/8 scale folded into Q projection.
// Workspace (bf16): Xq,Xk,Xv | Wq,Wk,Wv,Wo | Qp,Kp,Vt | AO  ~126 MB
// ---------------------------------------------------------------------------

typedef __bf16 bf16x8 __attribute__((ext_vector_type(8)));
typedef __bf16 bf16x4 __attribute__((ext_vector_type(4)));
typedef float  f32x4  __attribute__((ext_vector_type(4)));

#define MFMA16(a, b, c) __builtin_amdgcn_mfma_f32_16x16x32_bf16(a, b, c, 0, 0, 0)

constexpr int D_MODEL = 1024;
constexpr int SEQ     = 4096;
constexpr int BATCH   = 2;
constexpr int NH      = 16;
constexpr int DKH     = 64;
constexpr int MROWS   = BATCH * SEQ;  // 8192
constexpr int QT      = 256;          // q rows per attn block
constexpr int LROW    = 72;           // padded LDS row stride (bf16 elems)

// ---------------------------------------------------------------- cast kernel
__global__ void cast_f32_bf16(const float* __restrict__ in,
                              __bf16* __restrict__ out, int n) {
  int i = (blockIdx.x * 256 + threadIdx.x) * 4;
  if (i >= n) return;
  float4 v = *(const float4*)(in + i);
  bf16x4 o;
  o[0] = (__bf16)v.x; o[1] = (__bf16)v.y; o[2] = (__bf16)v.z; o[3] = (__bf16)v.w;
  *(bf16x4*)(out + i) = o;
}

// ------------------------------------------------------------------ GEMM (BT)
// C[M,N] = A[M,K] * W[N,K]^T + bias.  128x128 tile, BK=32, 4 waves (2x2).
// z==0 (Q proj): output scaled by 1/8 (fold softmax scale).
// z==2 (V proj): output written TRANSPOSED per (b,h): Vt[(b*1024+n)][s].
template <bool OUTF32>
__global__ __launch_bounds__(256) void gemm_bt(
    const __bf16* __restrict__ Abase, const __bf16* __restrict__ Wbase,
    const float* __restrict__ b0, const float* __restrict__ b1,
    const float* __restrict__ b2, void* __restrict__ Obase) {
  constexpr int K = 1024, N = 1024;
  const int z = blockIdx.z;
  const __bf16* A = Abase + (size_t)z * MROWS * K;
  const __bf16* W = Wbase + (size_t)z * N * K;
  const float* bias = (z == 0) ? b0 : (z == 1 ? b1 : b2);

  const int bm0 = blockIdx.x * 128, bn0 = blockIdx.y * 128;
  const int tid = threadIdx.x;
  const int lane = tid & 63, w = tid >> 6;
  const int wr = w >> 1, wc = w & 1;
  const int quad = lane >> 4, l15 = lane & 15;

  __shared__ __align__(16) __bf16 As[128 * 32];
  __shared__ __align__(16) __bf16 Bs[128 * 32];

  const int srow = tid >> 1;
  const int sc2 = (tid & 1) * 2;
  const __bf16* Ag = A + (size_t)(bm0 + srow) * K;
  const __bf16* Wg = W + (size_t)(bn0 + srow) * K;
  const int so0 = srow * 32 + (((sc2 + 0) ^ ((srow >> 1) & 3)) << 3);
  const int so1 = srow * 32 + (((sc2 + 1) ^ ((srow >> 1) & 3)) << 3);

  f32x4 acc[4][4];
  for (int i = 0; i < 4; i++)
    for (int j = 0; j < 4; j++) acc[i][j] = f32x4{0.f, 0.f, 0.f, 0.f};

  int aoff[4], boff[4];
  for (int i = 0; i < 4; i++) {
    int ra = wr * 64 + i * 16 + l15;
    aoff[i] = ra * 32 + ((quad ^ ((ra >> 1) & 3)) << 3);
    int rb = wc * 64 + i * 16 + l15;
    boff[i] = rb * 32 + ((quad ^ ((rb >> 1) & 3)) << 3);
  }

  for (int k0 = 0; k0 < K; k0 += 32) {
    uint4 av0 = *(const uint4*)(Ag + k0 + sc2 * 8);
    uint4 av1 = *(const uint4*)(Ag + k0 + sc2 * 8 + 8);
    uint4 bv0 = *(const uint4*)(Wg + k0 + sc2 * 8);
    uint4 bv1 = *(const uint4*)(Wg + k0 + sc2 * 8 + 8);
    __syncthreads();
    *(uint4*)(As + so0) = av0;
    *(uint4*)(As + so1) = av1;
    *(uint4*)(Bs + so0) = bv0;
    *(uint4*)(Bs + so1) = bv1;
    __syncthreads();
    bf16x8 af[4], bfr[4];
    for (int i = 0; i < 4; i++) af[i] = *(const bf16x8*)(As + aoff[i]);
    for (int j = 0; j < 4; j++) bfr[j] = *(const bf16x8*)(Bs + boff[j]);
    for (int i = 0; i < 4; i++)
      for (int j = 0; j < 4; j++) acc[i][j] = MFMA16(af[i], bfr[j], acc[i][j]);
  }

  // epilogue: C/D layout col=lane&15, row=quad*4+reg
  if (!OUTF32 && z == 2) {
    // transposed V write: Vt[(b*1024 + n)][s], n = h*64+d, row = b*4096+s
    __bf16* Vt = ((__bf16*)Obase) + (size_t)2 * MROWS * N;
    for (int j = 0; j < 4; j++) {
      int n = bn0 + wc * 64 + j * 16 + l15;
      float bv = bias[n];
      for (int i = 0; i < 4; i++) {
        int grow0 = bm0 + wr * 64 + i * 16 + quad * 4;  // multiple of 4
        int bb = grow0 >> 12, s = grow0 & 4095;
        bf16x4 ov;
        for (int r = 0; r < 4; r++) ov[r] = (__bf16)(acc[i][j][r] + bv);
        *(bf16x4*)(Vt + ((size_t)(bb * 1024 + n)) * SEQ + s) = ov;
      }
    }
  } else {
    const float scale = (!OUTF32 && z == 0) ? 0.125f : 1.0f;
    for (int j = 0; j < 4; j++) {
      int gcol = bn0 + wc * 64 + j * 16 + l15;
      float bv = bias[gcol];
      for (int i = 0; i < 4; i++) {
        int grow0 = bm0 + wr * 64 + i * 16 + quad * 4;
        for (int r = 0; r < 4; r++) {
          float v = (acc[i][j][r] + bv) * scale;
          size_t idx = (size_t)(grow0 + r) * N + gcol;
          if constexpr (OUTF32)
            ((float*)Obase)[idx] = v;
          else
            (((__bf16*)Obase) + (size_t)z * MROWS * N)[idx] = (__bf16)v;
        }
      }
    }
  }
}

// ----------------------------------------------------------- flash attention
// grid (S/256, NH, B), block 256 (4 waves). Wave w owns q cols [w*64, w*64+64).
// St = K*Q^T (A=K frags, B=Q frags; C: row=kv=quad*4+reg, col=q=lane&15).
// O^T = V^T*P^T accumulated in C-layout (row=d, col=q) — softmax stats (per q
// = per lane col) match O layout, no cross-lane transform.
// LDS rows stride 72 (16B-aligned, conflict-free by +8 pad). Ps overlaps Qs.
__global__ __launch_bounds__(256, 2) void attn_kernel(
    const __bf16* __restrict__ Q, const __bf16* __restrict__ K,
    const __bf16* __restrict__ Vt, __bf16* __restrict__ O) {
  const int qt = blockIdx.x, h = blockIdx.y, b = blockIdx.z;
  const __bf16* Qg = Q + ((size_t)b * SEQ + qt * QT) * D_MODEL + h * DKH;
  const __bf16* Kg = K + (size_t)b * SEQ * D_MODEL + h * DKH;
  const __bf16* Vg = Vt + ((size_t)b * D_MODEL + h * DKH) * SEQ;

  __shared__ __align__(16) __bf16 smem[QT * LROW + 2 * 64 * LROW];  // 54 KB
  __bf16* QPs = smem;              // Q tile, then reused as P (per-wave bands)
  __bf16* Ks  = smem + QT * LROW;
  __bf16* Vts = Ks + 64 * LROW;

  const int tid = threadIdx.x;
  const int lane = tid & 63, w = tid >> 6;
  const int quad = lane >> 4, l15 = lane & 15;
  const int srow = tid >> 2;      // staging row 0..63
  const int scb  = tid & 3;       // staging 32B slot

  // stage Q tile (256 rows x 64 d), 4 passes of 64 rows, 32B/thread
  for (int rr = 0; rr < 4; rr++) {
    int row = rr * 64 + srow;
    const __bf16* qg = Qg + (size_t)row * D_MODEL + scb * 16;
    uint4 v0 = *(const uint4*)(qg);
    uint4 v1 = *(const uint4*)(qg + 8);
    *(uint4*)(QPs + row * LROW + scb * 16) = v0;
    *(uint4*)(QPs + row * LROW + scb * 16 + 8) = v1;
  }
  __syncthreads();

  // hoist Q B-frags: B[k=d=quad*8+j+32ks][n=q=w*64+16jq+l15]
  bf16x8 qf[4][2];
  for (int jq = 0; jq < 4; jq++)
    for (int ks = 0; ks < 2; ks++)
      qf[jq][ks] =
          *(const bf16x8*)(QPs + (w * 64 + jq * 16 + l15) * LROW + (quad + 4 * ks) * 8);

  float m_[4], l_[4];
  f32x4 o_[4][4];  // o_[id][jq]: O^T[d=16id+quad*4+r][q=w*64+16jq+l15]
  for (int jq = 0; jq < 4; jq++) { m_[jq] = -__builtin_inff(); l_[jq] = 0.f; }
  for (int id = 0; id < 4; id++)
    for (int jq = 0; jq < 4; jq++) o_[id][jq] = f32x4{0.f, 0.f, 0.f, 0.f};

  for (int kt = 0; kt < SEQ / 64; ++kt) {
    // global loads first (hide latency across barrier)
    const __bf16* kg = Kg + (size_t)(kt * 64 + srow) * D_MODEL + scb * 16;
    const __bf16* vg = Vg + (size_t)srow * SEQ + kt * 64 + scb * 16;
    uint4 kv0 = *(const uint4*)(kg);
    uint4 kv1 = *(const uint4*)(kg + 8);
    uint4 vv0 = *(const uint4*)(vg);
    uint4 vv1 = *(const uint4*)(vg + 8);
    __syncthreads();  // prior iter's frag reads complete
    *(uint4*)(Ks + srow * LROW + scb * 16) = kv0;
    *(uint4*)(Ks + srow * LROW + scb * 16 + 8) = kv1;
    *(uint4*)(Vts + srow * LROW + scb * 16) = vv0;
    *(uint4*)(Vts + srow * LROW + scb * 16 + 8) = vv1;
    __syncthreads();

    // St[kv=64][q=64] = K * Q^T  (Q pre-scaled by 1/8 at projection)
    f32x4 st[4][4];  // st[i][jq]: rows 16i+quad*4+r, col 16jq+l15
    for (int i = 0; i < 4; i++) {
      bf16x8 kf0 = *(const bf16x8*)(Ks + (i * 16 + l15) * LROW + quad * 8);
      bf16x8 kf1 = *(const bf16x8*)(Ks + (i * 16 + l15) * LROW + (quad + 4) * 8);
      for (int jq = 0; jq < 4; jq++) {
        f32x4 c = f32x4{0.f, 0.f, 0.f, 0.f};
        c = MFMA16(kf0, qf[jq][0], c);
        c = MFMA16(kf1, qf[jq][1], c);
        st[i][jq] = c;
      }
    }

    // online softmax per q-column (lane col l15, per jq); kv spans (i,r,quad)
    for (int jq = 0; jq < 4; jq++) {
      float mx = st[0][jq][0];
      for (int i = 0; i < 4; i++)
        for (int r = 0; r < 4; r++) mx = fmaxf(mx, st[i][jq][r]);
      mx = fmaxf(mx, __shfl_xor(mx, 16));
      mx = fmaxf(mx, __shfl_xor(mx, 32));
      float mn = fmaxf(m_[jq], mx);
      float al = __expf(m_[jq] - mn);
      m_[jq] = mn;
      float rs = 0.f;
      for (int i = 0; i < 4; i++)
        for (int r = 0; r < 4; r++) {
          float p = __expf(st[i][jq][r] - mn);
          st[i][jq][r] = p;
          rs += p;
        }
      rs += __shfl_xor(rs, 16);
      rs += __shfl_xor(rs, 32);
      l_[jq] = l_[jq] * al + rs;
      for (int id = 0; id < 4; id++) o_[id][jq] *= al;
      // write P[q][kv] (wave-private rows w*64..): 4 consecutive kv per b64
      int prow = w * 64 + jq * 16 + l15;
      for (int i = 0; i < 4; i++) {
        bf16x4 pv;
        for (int r = 0; r < 4; r++) pv[r] = (__bf16)st[i][jq][r];
        *(bf16x4*)(QPs + prow * LROW + i * 16 + quad * 4) = pv;
      }
    }
    asm volatile("s_waitcnt lgkmcnt(0)" ::: "memory");  // P visible to own wave

    // O^T += V^T * P^T:  A=Vt[d][kv] frags, B=P[q][kv] rows read as B-frags
    for (int ks = 0; ks < 2; ks++) {
      bf16x8 pb[4];
      for (int jq = 0; jq < 4; jq++)
        pb[jq] = *(const bf16x8*)(QPs + (w * 64 + jq * 16 + l15) * LROW +
                                  (quad + 4 * ks) * 8);
      for (int id = 0; id < 4; id++) {
        bf16x8 va =
            *(const bf16x8*)(Vts + (id * 16 + l15) * LROW + (quad + 4 * ks) * 8);
        for (int jq = 0; jq < 4; jq++)
          o_[id][jq] = MFMA16(va, pb[jq], o_[id][jq]);
      }
    }
  }

  // epilogue: O^T[d][q] -> AO[q_global][h*64+d], /l, packed b64 stores
  for (int jq = 0; jq < 4; jq++) {
    float inv = 1.f / l_[jq];
    int grow = qt * QT + w * 64 + jq * 16 + l15;
    __bf16* og = O + ((size_t)b * SEQ + grow) * D_MODEL + h * DKH;
    for (int id = 0; id < 4; id++) {
      bf16x4 ov;
      for (int r = 0; r < 4; r++) ov[r] = (__bf16)(o_[id][jq][r] * inv);
      *(bf16x4*)(og + id * 16 + quad * 4) = ov;
    }
  }
}

// ---------------------------------------------------------------------------
extern "C" void kernel_launch(void* const* d_in, const int* in_sizes, int n_in,
                              void* d_out, int out_size, void* d_ws,
                              size_t ws_size, hipStream_t stream) {
  const float* q  = (const float*)d_in[0];
  const float* k  = (const float*)d_in[1];
  const float* v  = (const float*)d_in[2];
  const float* Wq = (const float*)d_in[3];
  const float* bq = (const float*)d_in[4];
  const float* Wk = (const float*)d_in[5];
  const float* bk = (const float*)d_in[6];
  const float* Wv = (const float*)d_in[7];
  const float* bv = (const float*)d_in[8];
  const float* Wo = (const float*)d_in[9];
  const float* bo = (const float*)d_in[10];

  const size_t MD = (size_t)MROWS * D_MODEL;
  const size_t WW = (size_t)D_MODEL * D_MODEL;

  __bf16* ws  = (__bf16*)d_ws;
  __bf16* Xq  = ws;
  __bf16* Xk  = Xq + MD;
  __bf16* Xv  = Xk + MD;
  __bf16* Wqb = Xv + MD;
  __bf16* Wkb = Wqb + WW;
  __bf16* Wvb = Wkb + WW;
  __bf16* Wob = Wvb + WW;
  __bf16* Qp  = Wob + WW;   // z=0 out; z=1 -> Kp = Qp+MD; z=2 -> Vt = Qp+2*MD
  __bf16* Kp  = Qp + MD;
  __bf16* Vtp = Kp + MD;    // transposed: [(b*1024 + h*64 + d)][s]
  __bf16* AO  = Vtp + MD;

  cast_f32_bf16<<<8192, 256, 0, stream>>>(q, Xq, (int)MD);
  cast_f32_bf16<<<8192, 256, 0, stream>>>(k, Xk, (int)MD);
  cast_f32_bf16<<<8192, 256, 0, stream>>>(v, Xv, (int)MD);
  cast_f32_bf16<<<1024, 256, 0, stream>>>(Wq, Wqb, (int)WW);
  cast_f32_bf16<<<1024, 256, 0, stream>>>(Wk, Wkb, (int)WW);
  cast_f32_bf16<<<1024, 256, 0, stream>>>(Wv, Wvb, (int)WW);
  cast_f32_bf16<<<1024, 256, 0, stream>>>(Wo, Wob, (int)WW);

  // fused QKV projections: z=0 Q(scaled 1/8), z=1 K, z=2 V^T
  gemm_bt<false><<<dim3(MROWS / 128, D_MODEL / 128, 3), 256, 0, stream>>>(
      Xq, Wqb, bq, bk, bv, (void*)Qp);

  attn_kernel<<<dim3(SEQ / QT, NH, BATCH), 256, 0, stream>>>(Qp, Kp, Vtp, AO);

  gemm_bt<true><<<dim3(MROWS / 128, D_MODEL / 128, 1), 256, 0, stream>>>(
      AO, Wob, bo, bo, bo, d_out);
}